// Round 11
// baseline (561.216 us; speedup 1.0000x reference)
//
#include <hip/hip_runtime.h>

// CombinedLoss: 0.7*MSE + 0.3*mean_b softDTW_gamma.  B=64, T=1024, C=8, fp32.
// R11: batch-pair ILP. 64 blocks x 256 thr (4 waves). Block = (pair, half):
// batches bA=pair, bB=pair+32; rows 512*half..+511 in 4 waves of 128 rows.
// Lane l owns rows rbase+2l, +2l+1 of BOTH batches (column sweep col j=s-l):
// per step 4 cells = two INDEPENDENT 2-deep softmin chains -> exp/log latency
// of one batch hidden under the other's issue (fixes R10's 1-chain stalls).
// Intra-block handoffs: full-length s_bot[wave][1024] rows + window fwd flags
// (no wraparound -> no credits -> deadlock-free DAG). Cross-block (half0->1):
// R10's self-validating u64 tag rings in ws. t columns prefetched 1 step ahead
// as float2 pairs; lane-0 halo = broadcast LDS read, prefetched.
// ws: [0,64) mse | [256,320) sdtw | u64 rings @ float-offset 320 (~512 KB).

constexpr int TT = 1024;
constexpr float ALPHA_ = 0.7f;
constexpr float FINF = 1000000000.0f;

__device__ __forceinline__ float shflup1(float old0, float v) {
    return __int_as_float(__builtin_amdgcn_update_dpp(
        __float_as_int(old0), __float_as_int(v), 0x138 /*wave_shr:1*/,
        0xf, 0xf, false));
}

template <int I> struct IC { static constexpr int v = I; };

__global__ __launch_bounds__(256) void sdtw_pair_kernel(
    const float* __restrict__ pred, const float* __restrict__ target,
    float* __restrict__ ws)
{
    __shared__ float2 s_tA[4][TT];    // (-2tA[2c], -2tA[2c+1]) per col
    __shared__ float  s_yA[TT];
    __shared__ float2 s_tB[4][TT];
    __shared__ float  s_yB[TT];
    __shared__ float  s_botA[4][TT];  // wave w bottom-row (rbase+127) values
    __shared__ float  s_botB[4][TT];
    __shared__ int    s_fwd[4];       // last window completed by wave w
    __shared__ float  s_red[4];

    const int blk = blockIdx.x;       // 0..63
    const int pr_ = blk >> 1;         // pair 0..31
    const int hf  = blk & 1;          // half 0..1
    const int bA  = pr_;
    const int bB  = pr_ + 32;
    const int tid = threadIdx.x;
    const int l   = tid & 63;
    const int w_  = __builtin_amdgcn_readfirstlane(tid >> 6);
    const int rbase = hf * 512 + w_ * 128;

    float pA0[8], pA1[8], pB0[8], pB1[8];
    float x2A0, x2A1, x2B0, x2B1;
    float msep = 0.f;

    auto loadrow = [&](int bb, int r, float* pp, float& xx) {
        const float* pb = pred   + ((size_t)bb * TT + r) * 8;
        const float* tb = target + ((size_t)bb * TT + r) * 8;
        const float4 u0 = ((const float4*)pb)[0];
        const float4 u1 = ((const float4*)pb)[1];
        const float4 v0 = ((const float4*)tb)[0];
        const float4 v1 = ((const float4*)tb)[1];
        const float P[8]  = {u0.x,u0.y,u0.z,u0.w,u1.x,u1.y,u1.z,u1.w};
        const float Tq[8] = {v0.x,v0.y,v0.z,v0.w,v1.x,v1.y,v1.z,v1.w};
        float s2 = 0.f;
        #pragma unroll
        for (int c = 0; c < 8; ++c) {
            pp[c] = P[c];
            s2 = fmaf(P[c], P[c], s2);
            const float d = P[c] - Tq[c];
            msep = fmaf(d, d, msep);
        }
        xx = s2;
    };
    loadrow(bA, rbase + 2*l,     pA0, x2A0);
    loadrow(bA, rbase + 2*l + 1, pA1, x2A1);
    loadrow(bB, rbase + 2*l,     pB0, x2B0);
    loadrow(bB, rbase + 2*l + 1, pB1, x2B1);

    #pragma unroll
    for (int k = 0; k < 4; ++k) {
        const int col = tid + (k << 8);
        {
            const float* tg = target + ((size_t)bA * TT + col) * 8;
            const float4 u0 = ((const float4*)tg)[0];
            const float4 u1 = ((const float4*)tg)[1];
            s_tA[0][col] = make_float2(-2.f*u0.x, -2.f*u0.y);
            s_tA[1][col] = make_float2(-2.f*u0.z, -2.f*u0.w);
            s_tA[2][col] = make_float2(-2.f*u1.x, -2.f*u1.y);
            s_tA[3][col] = make_float2(-2.f*u1.z, -2.f*u1.w);
            s_yA[col] = u0.x*u0.x+u0.y*u0.y+u0.z*u0.z+u0.w*u0.w
                      + u1.x*u1.x+u1.y*u1.y+u1.z*u1.z+u1.w*u1.w;
        }
        {
            const float* tg = target + ((size_t)bB * TT + col) * 8;
            const float4 u0 = ((const float4*)tg)[0];
            const float4 u1 = ((const float4*)tg)[1];
            s_tB[0][col] = make_float2(-2.f*u0.x, -2.f*u0.y);
            s_tB[1][col] = make_float2(-2.f*u0.z, -2.f*u0.w);
            s_tB[2][col] = make_float2(-2.f*u1.x, -2.f*u1.y);
            s_tB[3][col] = make_float2(-2.f*u1.z, -2.f*u1.w);
            s_yB[col] = u0.x*u0.x+u0.y*u0.y+u0.z*u0.z+u0.w*u0.w
                      + u1.x*u1.x+u1.y*u1.y+u1.z*u1.z+u1.w*u1.w;
        }
    }

    #pragma unroll
    for (int off = 32; off > 0; off >>= 1) msep += __shfl_down(msep, off, 64);
    if (l == 0) s_red[w_] = msep;
    if (tid < 4) s_fwd[tid] = -1;
    __syncthreads();
    if (tid == 0) ws[blk] = s_red[0] + s_red[1] + s_red[2] + s_red[3];

    unsigned long long* rings = (unsigned long long*)(ws + 320);
    unsigned long long* pubA = rings + (size_t)(pr_ * 2 + 0) * TT;
    unsigned long long* pubB = rings + (size_t)(pr_ * 2 + 1) * TT;

    const float c1 = 7.213475204444817f;     // log2(e)/gamma
    const float c2 = 0.13862943611198906f;   // gamma*ln(2)

    float lA0=FINF, lA1=FINF, lB0=FINF, lB1=FINF;
    float upprevA=FINF, upprevB=FINF;
    if (hf == 0 && w_ == 0 && l == 0) { upprevA = 0.f; upprevB = 0.f; }

    // prime current-t registers for s=0 (col clamp(0-l)=0)
    float2 tA0c=s_tA[0][0], tA1c=s_tA[1][0], tA2c=s_tA[2][0], tA3c=s_tA[3][0];
    float  yAc = s_yA[0];
    float2 tB0c=s_tB[0][0], tB1c=s_tB[1][0], tB2c=s_tB[2][0], tB3c=s_tB[3][0];
    float  yBc = s_yB[0];

    float hA=FINF, hB=FINF;
    float hvalA=FINF, hvalB=FINF;
    unsigned long long peA=0, peB=0;

    #define CELLF(UPV, LEV, DGV, ACC, OUT)                                   \
    {   const float m_  = fminf(fminf(UPV, LEV), DGV);                       \
        const float M_  = fmaxf(fmaxf(UPV, LEV), DGV);                       \
        const float d_  = __builtin_amdgcn_fmed3f(UPV, LEV, DGV);            \
        const float mc_ = m_ * c1;                                           \
        const float e1_ = __builtin_amdgcn_exp2f(fmaf(d_, -c1, mc_));        \
        const float e2_ = __builtin_amdgcn_exp2f(fmaf(M_, -c1, mc_));        \
        const float lg_ = __builtin_amdgcn_logf(1.0f + (e1_ + e2_));         \
        OUT = ACC + fmaf(-c2, lg_, m_); }

    auto runW = [&](auto MC) {
        constexpr int MODE = decltype(MC)::v;  // 0=top 1=LDS-halo 2=global
        for (int u = 0; u < 34; ++u) {
            if constexpr (MODE == 1) {
                if (u <= 31) {
                    const int need = (u + 2 < 33) ? (u + 2) : 33;
                    while (__hip_atomic_load(&s_fwd[w_-1], __ATOMIC_ACQUIRE,
                               __HIP_MEMORY_SCOPE_WORKGROUP) < need)
                        __builtin_amdgcn_s_sleep(1);
                    hA = s_botA[w_-1][u << 5];
                    hB = s_botB[w_-1][u << 5];
                }
            } else if constexpr (MODE == 2) {
                if (u <= 31) {
                    const int col = (u << 5) + l;
                    const bool need = (l < 32);
                    const int idx = col < TT ? col : TT - 1;
                    unsigned long long eA, eB;
                    if (u == 0) {
                        eA = __hip_atomic_load(pubA + idx, __ATOMIC_RELAXED,
                                               __HIP_MEMORY_SCOPE_AGENT);
                        eB = __hip_atomic_load(pubB + idx, __ATOMIC_RELAXED,
                                               __HIP_MEMORY_SCOPE_AGENT);
                    } else { eA = peA; eB = peB; }
                    while (!__all((!need) | (((int)(eA >> 32) == col) &
                                             ((int)(eB >> 32) == col)))) {
                        eA = __hip_atomic_load(pubA + idx, __ATOMIC_RELAXED,
                                               __HIP_MEMORY_SCOPE_AGENT);
                        eB = __hip_atomic_load(pubB + idx, __ATOMIC_RELAXED,
                                               __HIP_MEMORY_SCOPE_AGENT);
                    }
                    hvalA = __uint_as_float((unsigned)eA);
                    hvalB = __uint_as_float((unsigned)eB);
                    if (u < 31) {
                        peA = __hip_atomic_load(pubA + idx + 32, __ATOMIC_RELAXED,
                                                __HIP_MEMORY_SCOPE_AGENT);
                        peB = __hip_atomic_load(pubB + idx + 32, __ATOMIC_RELAXED,
                                                __HIP_MEMORY_SCOPE_AGENT);
                    }
                }
            }

            auto step = [&](int d, bool edge) {
                const int s = (u << 5) + d;
                float hsA, hsB;
                if constexpr (MODE == 0)      { hsA = FINF; hsB = FINF; }
                else if constexpr (MODE == 1) { hsA = hA;   hsB = hB; }
                else {
                    hsA = __int_as_float(__builtin_amdgcn_readlane(
                              __float_as_int(hvalA), d));
                    hsB = __int_as_float(__builtin_amdgcn_readlane(
                              __float_as_int(hvalB), d));
                }
                const float upA = shflup1(hsA, lA1);
                const float upB = shflup1(hsB, lB1);
                // prefetch next step's t (and halo)
                int jn = s + 1 - l;
                jn = jn < 0 ? 0 : (jn > TT - 1 ? TT - 1 : jn);
                const float2 fA0=s_tA[0][jn], fA1=s_tA[1][jn],
                             fA2=s_tA[2][jn], fA3=s_tA[3][jn];
                const float  fyA=s_yA[jn];
                const float2 fB0=s_tB[0][jn], fB1=s_tB[1][jn],
                             fB2=s_tB[2][jn], fB3=s_tB[3][jn];
                const float  fyB=s_yB[jn];
                float hAn = 0.f, hBn = 0.f;
                if constexpr (MODE == 1) {
                    const int sn = (s + 1 < TT) ? s + 1 : TT - 1;
                    hAn = s_botA[w_-1][sn];
                    hBn = s_botB[w_-1][sn];
                }
                // D values for the 4 cells (current-t regs)
                float aA0 = x2A0 + yAc, aA1 = x2A1 + yAc;
                aA0=fmaf(pA0[0],tA0c.x,aA0); aA0=fmaf(pA0[1],tA0c.y,aA0);
                aA0=fmaf(pA0[2],tA1c.x,aA0); aA0=fmaf(pA0[3],tA1c.y,aA0);
                aA0=fmaf(pA0[4],tA2c.x,aA0); aA0=fmaf(pA0[5],tA2c.y,aA0);
                aA0=fmaf(pA0[6],tA3c.x,aA0); aA0=fmaf(pA0[7],tA3c.y,aA0);
                aA1=fmaf(pA1[0],tA0c.x,aA1); aA1=fmaf(pA1[1],tA0c.y,aA1);
                aA1=fmaf(pA1[2],tA1c.x,aA1); aA1=fmaf(pA1[3],tA1c.y,aA1);
                aA1=fmaf(pA1[4],tA2c.x,aA1); aA1=fmaf(pA1[5],tA2c.y,aA1);
                aA1=fmaf(pA1[6],tA3c.x,aA1); aA1=fmaf(pA1[7],tA3c.y,aA1);
                float aB0 = x2B0 + yBc, aB1 = x2B1 + yBc;
                aB0=fmaf(pB0[0],tB0c.x,aB0); aB0=fmaf(pB0[1],tB0c.y,aB0);
                aB0=fmaf(pB0[2],tB1c.x,aB0); aB0=fmaf(pB0[3],tB1c.y,aB0);
                aB0=fmaf(pB0[4],tB2c.x,aB0); aB0=fmaf(pB0[5],tB2c.y,aB0);
                aB0=fmaf(pB0[6],tB3c.x,aB0); aB0=fmaf(pB0[7],tB3c.y,aB0);
                aB1=fmaf(pB1[0],tB0c.x,aB1); aB1=fmaf(pB1[1],tB0c.y,aB1);
                aB1=fmaf(pB1[2],tB1c.x,aB1); aB1=fmaf(pB1[3],tB1c.y,aB1);
                aB1=fmaf(pB1[4],tB2c.x,aB1); aB1=fmaf(pB1[5],tB2c.y,aB1);
                aB1=fmaf(pB1[6],tB3c.x,aB1); aB1=fmaf(pB1[7],tB3c.y,aB1);
                // two independent 2-deep chains
                float nA0v, nA1v, nB0v, nB1v;
                CELLF(upA,  lA0, upprevA, aA0, nA0v)
                CELLF(nA0v, lA1, lA0,     aA1, nA1v)
                CELLF(upB,  lB0, upprevB, aB0, nB0v)
                CELLF(nB0v, lB1, lB0,     aB1, nB1v)
                upprevA = upA; upprevB = upB;
                bool act = true;
                if (edge) act = ((unsigned)(s - l) < (unsigned)TT);
                lA0 = act ? nA0v : lA0;  lA1 = act ? nA1v : lA1;
                lB0 = act ? nB0v : lB0;  lB1 = act ? nB1v : lB1;
                // publish bottom row (lane 63)
                const int jp = s - 63;
                if (w_ < 3) {
                    if (l == 63 && (unsigned)jp < (unsigned)TT) {
                        s_botA[w_][jp] = lA1;
                        s_botB[w_][jp] = lB1;
                    }
                } else if (hf == 0) {
                    if (l == 63 && (unsigned)jp < (unsigned)TT) {
                        const unsigned long long evA =
                            ((unsigned long long)(unsigned)jp << 32) |
                            (unsigned long long)__float_as_uint(lA1);
                        const unsigned long long evB =
                            ((unsigned long long)(unsigned)jp << 32) |
                            (unsigned long long)__float_as_uint(lB1);
                        __hip_atomic_store(pubA + jp, evA, __ATOMIC_RELAXED,
                                           __HIP_MEMORY_SCOPE_AGENT);
                        __hip_atomic_store(pubB + jp, evB, __ATOMIC_RELAXED,
                                           __HIP_MEMORY_SCOPE_AGENT);
                    }
                }
                // rotate prefetched -> current
                tA0c=fA0; tA1c=fA1; tA2c=fA2; tA3c=fA3; yAc=fyA;
                tB0c=fB0; tB1c=fB1; tB2c=fB2; tB3c=fB3; yBc=fyB;
                if constexpr (MODE == 1) { hA = hAn; hB = hBn; }
            };

            if (u >= 2 && u <= 31) {
                #pragma unroll 8
                for (int d = 0; d < 32; ++d) step(d, false);
            } else {
                #pragma unroll 4
                for (int d = 0; d < 32; ++d) step(d, true);
            }

            if (w_ < 3 && l == 0)
                __hip_atomic_store(&s_fwd[w_], u, __ATOMIC_RELEASE,
                                   __HIP_MEMORY_SCOPE_WORKGROUP);
        }
    };

    if (w_ == 0) { if (hf == 0) runW(IC<0>{}); else runW(IC<2>{}); }
    else runW(IC<1>{});
    #undef CELLF

    if (hf == 1 && w_ == 3 && l == 63) {   // R[1023][1023] of both batches
        ws[256 + bA] = lA1;
        ws[256 + bB] = lB1;
    }
}

__global__ __launch_bounds__(64) void finalize3_kernel(
    const float* __restrict__ ws, float* __restrict__ out)
{
    const int t = threadIdx.x;
    float m  = ws[t];          // 64 block MSE partials
    float sd = ws[256 + t];    // 64 batch sdtw finals
    #pragma unroll
    for (int off = 32; off > 0; off >>= 1) {
        m  += __shfl_down(m,  off, 64);
        sd += __shfl_down(sd, off, 64);
    }
    if (t == 0)
        out[0] = ALPHA_ * (m / 524288.0f) + (1.0f - ALPHA_) * (sd / 64.0f);
}

extern "C" void kernel_launch(void* const* d_in, const int* in_sizes, int n_in,
                              void* d_out, int out_size, void* d_ws, size_t ws_size,
                              hipStream_t stream) {
    const float* pred   = (const float*)d_in[0];
    const float* target = (const float*)d_in[1];
    float* ws  = (float*)d_ws;
    float* out = (float*)d_out;

    sdtw_pair_kernel<<<64, 256, 0, stream>>>(pred, target, ws);
    finalize3_kernel<<<1, 64, 0, stream>>>(ws, out);
}

// Round 12
// 446.028 us; speedup vs baseline: 1.2583x; 1.2583x over previous
//
#include <hip/hip_runtime.h>

// CombinedLoss: 0.7*MSE + 0.3*mean_b softDTW_gamma.  B=64, T=1024, C=8, fp32.
// R12 = R9 self-timed wave pipeline + per-diagonal latency cuts:
//  (1) depth-2 t-column prefetch, loads issued FIRST in each diag body
//      (kills the ~120cy/diag exposed LDS RT that held all variants at
//       ~470 cy/diag vs ~110 theoretical)
//  (2) tree-reduced dot product (latency 16 vs 36)
//  (3) t-planes padded to 1092 cols -> no clamp in the address path
// Structure unchanged from R9 (passed): 4 bands x 64 batches = 256 blocks
// (4 waves), wave g=4q+w_ owns rows [64g,64g+63], 34 windows x 32 diags,
// LDS fwd/bwd flags intra-block, self-validating u64 tag rings cross-block.
// ws: [0,256) mse | [256,320) sdtw | u64 rings @ float-offset 320 (~1.67 MB).

constexpr int TT = 1024;
constexpr int NCOL = 1092;          // padded columns (max prefetch 1088)
constexpr float ALPHA_ = 0.7f;
constexpr float FINF = 1000000000.0f;
constexpr int RING = 1088;

__device__ __forceinline__ float shflup1(float old0, float v) {
    return __int_as_float(__builtin_amdgcn_update_dpp(
        __float_as_int(old0), __float_as_int(v), 0x138, 0xf, 0xf, false));
}
__device__ __forceinline__ float rotdn1(float v) {
    return __int_as_float(__builtin_amdgcn_update_dpp(
        0, __float_as_int(v), 0x130, 0xf, 0xf, false));
}

__global__ __launch_bounds__(256) void sdtw_band_kernel(
    const float* __restrict__ pred, const float* __restrict__ target,
    float* __restrict__ ws)
{
    __shared__ float4 s_p4[NCOL * 2];   // col j: [-2t0..3],[-2t4..7] (padded 0)
    __shared__ float  s_y2[NCOL];
    __shared__ float  s_ring[4][4][32]; // [wave][window&3][slot k&31]
    __shared__ float  s_scr[96];        // sink for non-lane63 halo writes
    __shared__ float  s_red[4];
    __shared__ int    s_fwd[4];
    __shared__ int    s_bwd[4];

    const int blk = blockIdx.x;
    const int b   = blk & 63;
    const int q   = blk >> 6;
    const int tid = threadIdx.x;
    const int l   = tid & 63;
    const int w_  = __builtin_amdgcn_readfirstlane(tid >> 6);
    const int g   = (q << 2) + w_;
    const int gbase = g << 6;
    const int row   = gbase + l;

    const float* pr = pred   + ((size_t)b * TT + row) * 8;
    const float* tr = target + ((size_t)b * TT + row) * 8;
    const float4 pa = ((const float4*)pr)[0];
    const float4 pb = ((const float4*)pr)[1];
    const float4 ma = ((const float4*)tr)[0];
    const float4 mb = ((const float4*)tr)[1];

    float x2 = 0.f, msep = 0.f;
    {
        const float pp[8] = {pa.x,pa.y,pa.z,pa.w,pb.x,pb.y,pb.z,pb.w};
        const float tt[8] = {ma.x,ma.y,ma.z,ma.w,mb.x,mb.y,mb.z,mb.w};
        #pragma unroll
        for (int c = 0; c < 8; ++c) {
            x2 = fmaf(pp[c], pp[c], x2);
            float d = pp[c] - tt[c];
            msep = fmaf(d, d, msep);
        }
    }
    const float* tg = target + (size_t)b * TT * 8;
    #pragma unroll
    for (int c0 = 0; c0 < 4; ++c0) {
        const int col = tid + (c0 << 8);
        const float4 u0 = ((const float4*)(tg + (size_t)col * 8))[0];
        const float4 u1 = ((const float4*)(tg + (size_t)col * 8))[1];
        s_p4[2*col]   = make_float4(-2.f*u0.x, -2.f*u0.y, -2.f*u0.z, -2.f*u0.w);
        s_p4[2*col+1] = make_float4(-2.f*u1.x, -2.f*u1.y, -2.f*u1.z, -2.f*u1.w);
        s_y2[col] = u0.x*u0.x + u0.y*u0.y + u0.z*u0.z + u0.w*u0.w
                  + u1.x*u1.x + u1.y*u1.y + u1.z*u1.z + u1.w*u1.w;
    }
    if (tid < NCOL - TT) {               // zero pad
        s_p4[2*(TT+tid)]   = make_float4(0.f,0.f,0.f,0.f);
        s_p4[2*(TT+tid)+1] = make_float4(0.f,0.f,0.f,0.f);
        s_y2[TT+tid] = 0.f;
    }
    #pragma unroll
    for (int off = 32; off > 0; off >>= 1) msep += __shfl_down(msep, off, 64);
    if (l == 0) s_red[w_] = msep;
    if (tid < 4) {
        s_fwd[tid] = -1;
        s_bwd[tid] = 8 * q + 2 * tid - 1;
    }
    __syncthreads();
    if (tid == 0) ws[blk] = s_red[0] + s_red[1] + s_red[2] + s_red[3];

    unsigned long long* rings = (unsigned long long*)(ws + 320);
    unsigned long long* pub = rings + (size_t)(q * 64 + b) * RING;
    unsigned long long* con = rings + (size_t)((q - 1) * 64 + b) * RING;
    const int kb_pub   = 256 * q + 192;
    const int kb_con   = 256 * q - 64;
    const int kmax_con = 256 * q + 1022;

    const float c1 = 7.213475204444817f;     // log2(e)/gamma
    const float c2 = 0.13862943611198906f;   // gamma*ln(2)

    float r1 = FINF, r2 = FINF;
    float tf0=0,tf1=0,tf2=0,tf3=0,tf4=0,tf5=0,tf6=0,tf7=0, y2f=0;
    // 3-slot column stream: cur (enters lane0 this diag), nxt, prefetch
    int jj0 = 0;
    float4 cA = s_p4[0], cB = s_p4[1];  float cy = s_y2[0];
    float4 nA = s_p4[2], nB = s_p4[3];  float ny = s_y2[1];
    unsigned long long pe1 = 0, pe2 = 0;
    int ppf = 0;

    const int amin = g << 1, amax = amin + 33;
    const int prodmax = amin + 31;
    const int klast = gbase + 63 + TT - 1;

    for (int a = amin; a <= amax; ++a) {
        const int k0 = a << 5;
        const int u  = a - amin;
        const int khi = min(k0 + 31, klast);
        const int ndv = khi - k0;

        if (w_ < 3) {
            while (__hip_atomic_load(&s_bwd[w_ + 1], __ATOMIC_ACQUIRE,
                       __HIP_MEMORY_SCOPE_WORKGROUP) < a - 3)
                __builtin_amdgcn_s_sleep(1);
        }

        float hv, hvd;
        if (w_ == 0) {
            if (q == 0) {
                hv  = FINF;
                hvd = (a == 0 && l == 0) ? 0.0f : FINF;
            } else {
                const int kk1 = k0 - 1 + l, kk2 = k0 - 2 + l;
                const int id1 = min(kk1 - kb_con, RING - 1);
                const int id2 = min(kk2 - kb_con, RING - 1);
                const bool n1 = (l < 32) && (kk1 <= kmax_con);
                const bool n2 = (l < 32) && (kk2 <= kmax_con);
                unsigned long long e1, e2;
                if (ppf) { e1 = pe1; e2 = pe2; ppf = 0; }
                else {
                    e1 = __hip_atomic_load(con + id1, __ATOMIC_RELAXED,
                                           __HIP_MEMORY_SCOPE_AGENT);
                    e2 = __hip_atomic_load(con + id2, __ATOMIC_RELAXED,
                                           __HIP_MEMORY_SCOPE_AGENT);
                }
                while (!__all(((!n1) | ((int)(e1 >> 32) == kk1)) &
                              ((!n2) | ((int)(e2 >> 32) == kk2)))) {
                    e1 = __hip_atomic_load(con + id1, __ATOMIC_RELAXED,
                                           __HIP_MEMORY_SCOPE_AGENT);
                    e2 = __hip_atomic_load(con + id2, __ATOMIC_RELAXED,
                                           __HIP_MEMORY_SCOPE_AGENT);
                }
                hv  = n1 ? __uint_as_float((unsigned)e1) : FINF;
                hvd = n2 ? __uint_as_float((unsigned)e2) : FINF;
                if (a < amax) {
                    const int kn = k0 + 32;
                    pe1 = __hip_atomic_load(con + min(kn - 1 + l - kb_con, RING - 1),
                                            __ATOMIC_RELAXED, __HIP_MEMORY_SCOPE_AGENT);
                    pe2 = __hip_atomic_load(con + min(kn - 2 + l - kb_con, RING - 1),
                                            __ATOMIC_RELAXED, __HIP_MEMORY_SCOPE_AGENT);
                    ppf = 1;
                }
            }
        } else {
            const int need_f = min(a, prodmax);
            while (__hip_atomic_load(&s_fwd[w_ - 1], __ATOMIC_ACQUIRE,
                       __HIP_MEMORY_SCOPE_WORKGROUP) < need_f)
                __builtin_amdgcn_s_sleep(1);
            const int kk1 = k0 - 1 + l, kk2 = k0 - 2 + l;
            hv  = s_ring[w_ - 1][(kk1 >> 5) & 3][kk1 & 31];
            hvd = s_ring[w_ - 1][(kk2 >> 5) & 3][kk2 & 31];
            if (l == 0)
                __hip_atomic_store(&s_bwd[w_], a, __ATOMIC_RELEASE,
                                   __HIP_MEMORY_SCOPE_WORKGROUP);
        }
        float* wrp = (l == 63) ? &s_ring[w_][a & 3][0] : &s_scr[l];

        auto diag = [&](int d, bool edge_) {
            // (1) prefetch FIRST: column jj0+2 (pad guarantees in-bounds)
            const float4 fA = s_p4[2*(jj0+2)];
            const float4 fB = s_p4[2*(jj0+2)+1];
            const float  fy = s_y2[jj0+2];
            // t-flow + r DPPs (use cur slot, loaded 2 steps ago)
            tf0 = shflup1(cA.x, tf0); tf1 = shflup1(cA.y, tf1);
            tf2 = shflup1(cA.z, tf2); tf3 = shflup1(cA.w, tf3);
            tf4 = shflup1(cB.x, tf4); tf5 = shflup1(cB.y, tf5);
            tf6 = shflup1(cB.z, tf6); tf7 = shflup1(cB.w, tf7);
            y2f = shflup1(cy, y2f);
            const float up   = shflup1(hv,  r1);
            const float dg   = shflup1(hvd, r2);
            const float left = r1;
            hv = rotdn1(hv); hvd = rotdn1(hvd);
            // (2) tree dot
            const float m01 = fmaf(pa.y, tf1, pa.x * tf0);
            const float m23 = fmaf(pa.w, tf3, pa.z * tf2);
            const float m45 = fmaf(pb.y, tf5, pb.x * tf4);
            const float m67 = fmaf(pb.w, tf7, pb.z * tf6);
            const float bse = x2 + y2f;
            const float acc = (bse + (m01 + m23)) + (m45 + m67);
            const float m  = fminf(fminf(up, left), dg);
            const float M  = fmaxf(fmaxf(up, left), dg);
            const float md = __builtin_amdgcn_fmed3f(up, left, dg);
            const float mc = m * c1;
            const float e1 = __builtin_amdgcn_exp2f(fmaf(md, -c1, mc));
            const float e2 = __builtin_amdgcn_exp2f(fmaf(M,  -c1, mc));
            const float lg = __builtin_amdgcn_logf(1.0f + (e1 + e2));
            float rn = acc + fmaf(-c2, lg, m);
            if (edge_) {
                const int jj = (jj0 + gbase) - row;   // j of this lane
                rn = ((unsigned)jj < (unsigned)TT) ? rn : FINF;
            }
            r2 = r1; r1 = rn;
            wrp[d] = rn;
            // rotate slots
            cA = nA; cB = nB; cy = ny;
            nA = fA; nB = fB; ny = fy;
            ++jj0;
        };

        if (u >= 2 && u <= 31) {
            #pragma unroll 8
            for (int d = 0; d < 32; ++d) diag(d, false);
        } else {
            for (int d = 0; d <= ndv; ++d) diag(d, true);
        }

        if (w_ < 3) {
            if (l == 0)
                __hip_atomic_store(&s_fwd[w_], a, __ATOMIC_RELEASE,
                                   __HIP_MEMORY_SCOPE_WORKGROUP);
        } else if (q < 3) {
            if (l <= ndv) {
                const int kk = k0 + l;
                const unsigned long long ev =
                    ((unsigned long long)(unsigned)kk << 32) |
                    (unsigned long long)__float_as_uint(s_ring[3][a & 3][l]);
                __hip_atomic_store(pub + (kk - kb_pub), ev,
                                   __ATOMIC_RELAXED, __HIP_MEMORY_SCOPE_AGENT);
            }
        }
    }
    if (q == 3 && tid == 255) ws[256 + b] = r1;

}

__global__ __launch_bounds__(256) void finalize2_kernel(
    const float* __restrict__ ws, float* __restrict__ out)
{
    __shared__ float sm[4], ss[4];
    const int tid = threadIdx.x, l = tid & 63, w = tid >> 6;
    float m  = ws[tid];
    float sd = (tid < 64) ? ws[256 + tid] : 0.f;
    #pragma unroll
    for (int off = 32; off > 0; off >>= 1) {
        m  += __shfl_down(m,  off, 64);
        sd += __shfl_down(sd, off, 64);
    }
    if (l == 0) { sm[w] = m; ss[w] = sd; }
    __syncthreads();
    if (tid == 0) {
        float M = sm[0] + sm[1] + sm[2] + sm[3];
        float S = ss[0] + ss[1] + ss[2] + ss[3];
        out[0] = ALPHA_ * (M / 524288.0f) + (1.0f - ALPHA_) * (S / 64.0f);
    }
}

extern "C" void kernel_launch(void* const* d_in, const int* in_sizes, int n_in,
                              void* d_out, int out_size, void* d_ws, size_t ws_size,
                              hipStream_t stream) {
    const float* pred   = (const float*)d_in[0];
    const float* target = (const float*)d_in[1];
    float* ws  = (float*)d_ws;
    float* out = (float*)d_out;

    sdtw_band_kernel<<<256, 256, 0, stream>>>(pred, target, ws);
    finalize2_kernel<<<1, 256, 0, stream>>>(ws, out);
}